// Round 3
// baseline (366.754 us; speedup 1.0000x reference)
//
#include <hip/hip_runtime.h>

#define OUT_SZ 299
#define PLANE (OUT_SZ * OUT_SZ)   // 89401

__global__ __launch_bounds__(256) void crop_resize_kernel(
    const float* __restrict__ x,   // (32, 3, 299, 299)
    const int*   __restrict__ f,   // (32, 16, 4) = tlx, tly, brx, bry
    float*       __restrict__ out) // (32, 16, 3, 299, 299)
{
    const int pix = blockIdx.x * blockDim.x + threadIdx.x;
    if (pix >= PLANE) return;

    const int c  = blockIdx.y;   // channel 0..2
    const int sg = blockIdx.z;   // s*16 + g, 0..511
    const int s  = sg >> 4;

    // Box is block-uniform (indexed by blockIdx.z) -> scalar loads.
    const int4 box = *reinterpret_cast<const int4*>(f + (size_t)sg * 4);
    const int tlx = box.x, tly = box.y, brx = box.z, bry = box.w;

    const float hc = (float)(brx - tlx);   // crop height (rows)
    const float wc = (float)(bry - tly);   // crop width  (cols)

    const int i = pix / OUT_SZ;            // output row
    const int j = pix - i * OUT_SZ;        // output col

    // Half-pixel mapping, clamped to crop interior, then shifted by tl.
    float src_r = fminf(fmaxf(((float)i + 0.5f) * hc / (float)OUT_SZ - 0.5f, 0.0f),
                        hc - 1.0f) + (float)tlx;
    float src_c = fminf(fmaxf(((float)j + 0.5f) * wc / (float)OUT_SZ - 0.5f, 0.0f),
                        wc - 1.0f) + (float)tly;

    float r0f = floorf(src_r);
    float c0f = floorf(src_c);
    float wr  = src_r - r0f;   // row frac weight
    float wcl = src_c - c0f;   // col frac weight

    int r0 = (int)r0f;
    int c0 = (int)c0f;
    int r1 = min(r0 + 1, brx - 1);
    int c1 = min(c0 + 1, bry - 1);

    const float* img  = x + ((size_t)s * 3 + (size_t)c) * PLANE;
    const float* row0 = img + (size_t)r0 * OUT_SZ;
    const float* row1 = img + (size_t)r1 * OUT_SZ;

    float top = row0[c0] * (1.0f - wcl) + row0[c1] * wcl;
    float bot = row1[c0] * (1.0f - wcl) + row1[c1] * wcl;
    float v   = top * (1.0f - wr) + bot * wr;

    out[((size_t)sg * 3 + (size_t)c) * PLANE + (size_t)pix] = v;
}

extern "C" void kernel_launch(void* const* d_in, const int* in_sizes, int n_in,
                              void* d_out, int out_size, void* d_ws, size_t ws_size,
                              hipStream_t stream) {
    const float* x   = (const float*)d_in[0];  // (32,3,299,299) fp32
    const int*   f   = (const int*)  d_in[1];  // (32,16,4) int32
    float*       out = (float*)d_out;          // (32,16,3,299,299) fp32

    dim3 grid((PLANE + 255) / 256, 3, 32 * 16);
    crop_resize_kernel<<<grid, 256, 0, stream>>>(x, f, out);
}

// Round 4
// 268.338 us; speedup vs baseline: 1.3668x; 1.3668x over previous
//
#include <hip/hip_runtime.h>

#define OUT_SZ 299
#define PLANE (OUT_SZ * OUT_SZ)   // 89401
#define RPB 13                    // rows per block: 13 * 23 = 299
#define CHUNKS 23

struct __align__(16) RowInfo {
    int   r0e;   // r0 * 299 (element offset of top row)
    int   r1e;   // r1 * 299 (element offset of bottom row)
    float wr;    // row frac weight
    float pad;
};

__global__ __launch_bounds__(320) void crop_resize_kernel(
    const float* __restrict__ x,   // (32, 3, 299, 299)
    const int*   __restrict__ f,   // (32, 16, 4) = tlx, tly, brx, bry
    float*       __restrict__ out) // (32, 16, 3, 299, 299)
{
    __shared__ RowInfo rows[RPB];

    const int t     = threadIdx.x;   // column index (t < 299 active)
    const int chunk = blockIdx.x;    // 0..22 row chunk
    const int c     = blockIdx.y;    // channel 0..2
    const int sg    = blockIdx.z;    // s*16 + g
    const int s     = sg >> 4;

    // Box is block-uniform -> scalar loads.
    const int4 box = *reinterpret_cast<const int4*>(f + (size_t)sg * 4);
    const int tlx = box.x, tly = box.y, brx = box.z, bry = box.w;
    const float hc = (float)(brx - tlx);   // crop height (rows)
    const float wc = (float)(bry - tly);   // crop width  (cols)

    // Per-row precompute: 13 rows, once per block.
    if (t < RPB) {
        const int i = chunk * RPB + t;
        float src_r = fminf(fmaxf(((float)i + 0.5f) * hc / (float)OUT_SZ - 0.5f,
                                  0.0f), hc - 1.0f) + (float)tlx;
        float r0f = floorf(src_r);
        int   r0  = (int)r0f;
        rows[t].r0e = r0 * OUT_SZ;
        rows[t].r1e = min(r0 + 1, brx - 1) * OUT_SZ;
        rows[t].wr  = src_r - r0f;
        rows[t].pad = 0.0f;
    }
    __syncthreads();

    if (t >= OUT_SZ) return;   // no further syncs; safe to retire

    // Per-column precompute: once per thread, stays in registers.
    float src_c = fminf(fmaxf(((float)t + 0.5f) * wc / (float)OUT_SZ - 0.5f,
                              0.0f), wc - 1.0f) + (float)tly;
    float c0f = floorf(src_c);
    const int   c0   = (int)c0f;
    const int   c1   = min(c0 + 1, bry - 1);
    const float wcl  = src_c - c0f;
    const float iwcl = 1.0f - wcl;

    const float* __restrict__ img = x + ((size_t)s * 3 + (size_t)c) * PLANE;
    float* __restrict__ orow = out + ((size_t)sg * 3 + (size_t)c) * PLANE
                             + (size_t)(chunk * RPB) * OUT_SZ + t;

    #pragma unroll
    for (int rr = 0; rr < RPB; ++rr) {
        const RowInfo ri = rows[rr];          // one broadcast ds_read_b128
        const float* p0 = img + ri.r0e;
        const float* p1 = img + ri.r1e;
        float top = p0[c0] * iwcl + p0[c1] * wcl;
        float bot = p1[c0] * iwcl + p1[c1] * wcl;
        orow[(size_t)rr * OUT_SZ] = top * (1.0f - ri.wr) + bot * ri.wr;
    }
}

extern "C" void kernel_launch(void* const* d_in, const int* in_sizes, int n_in,
                              void* d_out, int out_size, void* d_ws, size_t ws_size,
                              hipStream_t stream) {
    const float* x   = (const float*)d_in[0];  // (32,3,299,299) fp32
    const int*   f   = (const int*)  d_in[1];  // (32,16,4) int32
    float*       out = (float*)d_out;          // (32,16,3,299,299) fp32

    dim3 grid(CHUNKS, 3, 32 * 16);
    crop_resize_kernel<<<grid, 320, 0, stream>>>(x, f, out);
}

// Round 5
// 154.581 us; speedup vs baseline: 2.3726x; 1.7359x over previous
//
#include <hip/hip_runtime.h>

#define OUT_SZ 299
#define PLANE (OUT_SZ * OUT_SZ)   // 89401
#define RPB 13                    // output rows per block: 13 * 23 = 299
#define CHUNKS 23
#define NR 10                     // max distinct input rows per chunk:
                                  // 12 * (199/299) + 2 = 9.99 -> 10

struct __align__(16) RowInfo {
    int   off0b;  // LDS byte offset of h-row for r0
    int   off1b;  // LDS byte offset of h-row for r1
    float wr;     // row frac weight
    float iwr;    // 1 - wr
};

__global__ __launch_bounds__(320) void crop_resize_kernel(
    const float* __restrict__ x,   // (32, 3, 299, 299)
    const int*   __restrict__ f,   // (32, 16, 4) = tlx, tly, brx, bry
    float*       __restrict__ out) // (32, 16, 3, 299, 299)
{
    __shared__ float   h[NR * OUT_SZ];   // horizontally-interpolated rows, 12 KB
    __shared__ RowInfo rows[RPB];

    const int t     = threadIdx.x;   // output column (t < 299 active)
    const int chunk = blockIdx.x;    // 0..22
    const int c     = blockIdx.y;    // channel
    const int sg    = blockIdx.z;    // s*16 + g
    const int s     = sg >> 4;

    // Box is block-uniform -> scalar.
    const int4 box = *reinterpret_cast<const int4*>(f + (size_t)sg * 4);
    const int tlx = box.x, tly = box.y, brx = box.z, bry = box.w;
    const int hcI = brx - tlx, wcI = bry - tly;
    const float hc = (float)hcI, wc = (float)wcI;

    // Uniform: first input row touched by this chunk.
    const int i0 = chunk * RPB;
    const float sr0 = fminf(fmaxf(((float)i0 + 0.5f) * hc / (float)OUT_SZ - 0.5f,
                                  0.0f), hc - 1.0f);
    const int rbase = (int)floorf(sr0);

    // Per-output-row info (13 rows) -> LDS.
    if (t < RPB) {
        const int i = i0 + t;
        float sr  = fminf(fmaxf(((float)i + 0.5f) * hc / (float)OUT_SZ - 0.5f,
                                0.0f), hc - 1.0f);
        float r0f = floorf(sr);
        int   r0  = (int)r0f;
        int   r1  = min(r0 + 1, hcI - 1);
        int   s0  = min(max(r0 - rbase, 0), NR - 1);   // clamp for safety
        int   s1  = min(max(r1 - rbase, 0), NR - 1);
        rows[t].off0b = s0 * (OUT_SZ * 4);
        rows[t].off1b = s1 * (OUT_SZ * 4);
        float wr = sr - r0f;
        rows[t].wr  = wr;
        rows[t].iwr = 1.0f - wr;
    }

    // Per-column precompute: once per thread, registers only.
    float sc  = fminf(fmaxf(((float)t + 0.5f) * wc / (float)OUT_SZ - 0.5f,
                            0.0f), wc - 1.0f);
    float c0f = floorf(sc);
    const int   c0   = (int)c0f + tly;
    const int   c1   = min((int)c0f + 1, wcI - 1) + tly;
    const float wcl  = sc - c0f;
    const float iwcl = 1.0f - wcl;

    const float* __restrict__ img = x + ((size_t)s * 3 + (size_t)c) * PLANE;

    // Build h: col-interp each needed input row ONCE (<=10 rows, 2 gathers each).
    if (t < OUT_SZ) {
        #pragma unroll
        for (int rr = 0; rr < NR; ++rr) {
            const int rl = min(rbase + rr, hcI - 1) + tlx;   // clamped input row
            const float* p = img + (size_t)rl * OUT_SZ;
            h[rr * OUT_SZ + t] = p[c0] * iwcl + p[c1] * wcl;
        }
    }
    __syncthreads();
    if (t >= OUT_SZ) return;

    float* __restrict__ orow = out + ((size_t)sg * 3 + (size_t)c) * PLANE
                             + (size_t)i0 * OUT_SZ + t;
    const char* hT = reinterpret_cast<const char*>(h + t);

    #pragma unroll
    for (int rr = 0; rr < RPB; ++rr) {
        const RowInfo ri = rows[rr];   // uniform broadcast ds_read_b128
        float h0 = *reinterpret_cast<const float*>(hT + ri.off0b);
        float h1 = *reinterpret_cast<const float*>(hT + ri.off1b);
        orow[(size_t)rr * OUT_SZ] = h0 * ri.iwr + h1 * ri.wr;
    }
}

extern "C" void kernel_launch(void* const* d_in, const int* in_sizes, int n_in,
                              void* d_out, int out_size, void* d_ws, size_t ws_size,
                              hipStream_t stream) {
    const float* x   = (const float*)d_in[0];  // (32,3,299,299) fp32
    const int*   f   = (const int*)  d_in[1];  // (32,16,4) int32
    float*       out = (float*)d_out;          // (32,16,3,299,299) fp32

    dim3 grid(CHUNKS, 3, 32 * 16);
    crop_resize_kernel<<<grid, 320, 0, stream>>>(x, f, out);
}